// Round 16
// baseline (260.146 us; speedup 1.0000x reference)
//
#include <hip/hip_runtime.h>
#include <hip/hip_bf16.h>

#define B_ 4
#define T_ 2048
#define C_ 1024
#define H_ 16
#define HD_ 64
#define M_ (B_*T_)   // 8192

typedef __attribute__((ext_vector_type(8))) short short8;
typedef __attribute__((ext_vector_type(4))) float f32x4;
typedef __attribute__((ext_vector_type(16))) float f32x16;
typedef __attribute__((ext_vector_type(4))) unsigned int u32x4;
typedef unsigned short u16;
typedef unsigned int u32;

__device__ __forceinline__ u16 f2bf(float f){
  unsigned int x = __builtin_bit_cast(unsigned int, f);
  x += 0x7fffu + ((x >> 16) & 1u);   // RNE
  return (u16)(x >> 16);
}

__device__ __forceinline__ u32 cvtpk(float lo, float hi){
  u32 r;
  asm("v_cvt_pk_bf16_f32 %0, %1, %2" : "=v"(r) : "v"(lo), "v"(hi));
  return r;
}

// async global->LDS, 16B per lane; LDS dest must be wave-uniform base + lane*16
#define GLOAD_LDS(gsrc, ldst) \
  __builtin_amdgcn_global_load_lds((const __attribute__((address_space(1))) u32*)(gsrc), \
                                   (__attribute__((address_space(3))) u32*)(ldst), 16, 0, 0)

// ---------------- fused fp32 -> bf16 convert (x, w_qkv, w_proj in one grid) ----
__global__ __launch_bounds__(256)
void cvt3_kernel(const float* __restrict__ x, const float* __restrict__ w1,
                 const float* __restrict__ w2, u16* __restrict__ xb,
                 u16* __restrict__ w1b, u16* __restrict__ w2b){
  int i = blockIdx.x * 256 + threadIdx.x;
  const float* src; u16* dst; int off;
  if (i < 2097152)              { src = x;  dst = xb;  off = i; }
  else if (i < 2097152 + 786432){ src = w1; dst = w1b; off = i - 2097152; }
  else                          { src = w2; dst = w2b; off = i - (2097152 + 786432); }
  float4 f = reinterpret_cast<const float4*>(src)[off];
  ushort4 u;
  u.x = f2bf(f.x); u.y = f2bf(f.y); u.z = f2bf(f.z); u.w = f2bf(f.w);
  reinterpret_cast<ushort4*>(dst)[off] = u;
}

// ---------------- 256x256 GEMM: C[M,N] = A[M,K]*Bt[N,K]^T + bias ----------------
// 8 waves (2Mx4N), BK=64, double-buffered 128KiB LDS, ONE barrier per K-tile:
// next tile's 8 global_load_lds issue right after the barrier and drain at the
// NEXT tile's barrier (4 phases of flight). T2 swizzle rule-#21 both-sides:
// linear LDS dest + source col-slot ^(row&7) + same XOR on ds_read (verified
// 8-touches/bank = conflict-free). Phases reuse frags: 28 b128/K-tile.
// MODE 0: scatter q/k/v bf16 (Q pre-scaled 0.125*log2e).  MODE 1: fp32 out.
template<int MODE>
__global__ __launch_bounds__(512, 2)
void gemm256(const u16* __restrict__ A, const u16* __restrict__ Bt,
             const float* __restrict__ bias, float* __restrict__ Cf,
             u16* __restrict__ Qo, u16* __restrict__ Ko, u16* __restrict__ Vo,
             int N, int K)
{
  __shared__ u16 As[2 * 16384];   // [buf][256 rows][64 cols], linear per buf
  __shared__ u16 Bs[2 * 16384];
  const int tid = threadIdx.x;
  const int wid = tid >> 6, lane = tid & 63;
  const int lo = lane & 15, hi = lane >> 4;
  const int wr = wid >> 2, wc = wid & 3;      // 2x4 wave grid
  const int NBN = N >> 8;
  const int cpx = gridDim.x >> 3;             // gridDim.x % 8 == 0
  const int swz = (blockIdx.x & 7) * cpx + (blockIdx.x >> 3);   // T1 bijective
  const long bm = (long)(swz / NBN) << 8;
  const long bn = (long)(swz % NBN) << 8;

  f32x4 acc[8][4];
  #pragma unroll
  for (int mi = 0; mi < 8; mi++)
    #pragma unroll
    for (int ni = 0; ni < 4; ni++)
      acc[mi][ni] = (f32x4){0.f, 0.f, 0.f, 0.f};

  // stage one K-tile (4 half-tiles, 8 gload_lds/thread). chunk=(row*8+slot);
  // LDS dest linear (wave-uniform+lane*16); source col-slot pre-swizzled.
  #define STAGE256(bufsel, k0s) do {                                           \
    _Pragma("unroll")                                                          \
    for (int j = 0; j < 2; j++){                                               \
      const int row  = j * 64 + (tid >> 3);                                    \
      const int slot = tid & 7;                                                \
      const int scol = (slot ^ (row & 7)) << 3;                                \
      const int doff = (bufsel) * 16384 + ((row << 3) + slot) * 8;             \
      GLOAD_LDS(&A [(bm +       row) * K + (k0s) + scol], &As[doff]);          \
      GLOAD_LDS(&A [(bm + 128 + row) * K + (k0s) + scol], &As[doff + 8192]);   \
      GLOAD_LDS(&Bt[(bn +       row) * K + (k0s) + scol], &Bs[doff]);          \
      GLOAD_LDS(&Bt[(bn + 128 + row) * K + (k0s) + scol], &Bs[doff + 8192]);   \
    }                                                                          \
  } while (0)

  const int NK = K >> 6;
  STAGE256(0, 0);

  const int sx = lo & 7;                       // row&7 for all frag reads
  short8 af[4][2], bf[2][2];

  for (int kt = 0; kt < NK; kt++){
    const int cb = kt & 1;
    __syncthreads();                           // drains vmcnt(0): tile kt ready; buf cb^1 free
    if (kt + 1 < NK) STAGE256(cb ^ 1, (kt + 1) << 6);

    const u16* Ab = &As[cb * 16384];
    const u16* Bb = &Bs[cb * 16384];

    // ---- p0: A(mi0-3), B(ni0-1) -> acc[0-3][0-1] ----
    #pragma unroll
    for (int mi = 0; mi < 4; mi++)
      #pragma unroll
      for (int kk = 0; kk < 2; kk++)
        af[mi][kk] = *reinterpret_cast<const short8*>(
          &Ab[(wr*128 + mi*16 + lo) * 64 + ((((kk<<2)+hi) ^ sx) << 3)]);
    #pragma unroll
    for (int ni = 0; ni < 2; ni++)
      #pragma unroll
      for (int kk = 0; kk < 2; kk++)
        bf[ni][kk] = *reinterpret_cast<const short8*>(
          &Bb[(wc*64 + ni*16 + lo) * 64 + ((((kk<<2)+hi) ^ sx) << 3)]);
    __builtin_amdgcn_s_setprio(1);
    #pragma unroll
    for (int mi = 0; mi < 4; mi++)
      #pragma unroll
      for (int ni = 0; ni < 2; ni++)
        #pragma unroll
        for (int kk = 0; kk < 2; kk++)
          acc[mi][ni] = __builtin_amdgcn_mfma_f32_16x16x32_bf16(af[mi][kk], bf[ni][kk], acc[mi][ni], 0, 0, 0);
    __builtin_amdgcn_s_setprio(0);

    // ---- p1: B(ni2-3) -> acc[0-3][2-3] ----
    #pragma unroll
    for (int ni = 0; ni < 2; ni++)
      #pragma unroll
      for (int kk = 0; kk < 2; kk++)
        bf[ni][kk] = *reinterpret_cast<const short8*>(
          &Bb[(wc*64 + (ni+2)*16 + lo) * 64 + ((((kk<<2)+hi) ^ sx) << 3)]);
    __builtin_amdgcn_s_setprio(1);
    #pragma unroll
    for (int mi = 0; mi < 4; mi++)
      #pragma unroll
      for (int ni = 0; ni < 2; ni++)
        #pragma unroll
        for (int kk = 0; kk < 2; kk++)
          acc[mi][ni+2] = __builtin_amdgcn_mfma_f32_16x16x32_bf16(af[mi][kk], bf[ni][kk], acc[mi][ni+2], 0, 0, 0);
    __builtin_amdgcn_s_setprio(0);

    // ---- p2: A(mi4-7) -> acc[4-7][2-3] ----
    #pragma unroll
    for (int mi = 0; mi < 4; mi++)
      #pragma unroll
      for (int kk = 0; kk < 2; kk++)
        af[mi][kk] = *reinterpret_cast<const short8*>(
          &Ab[(wr*128 + (mi+4)*16 + lo) * 64 + ((((kk<<2)+hi) ^ sx) << 3)]);
    __builtin_amdgcn_s_setprio(1);
    #pragma unroll
    for (int mi = 0; mi < 4; mi++)
      #pragma unroll
      for (int ni = 0; ni < 2; ni++)
        #pragma unroll
        for (int kk = 0; kk < 2; kk++)
          acc[mi+4][ni+2] = __builtin_amdgcn_mfma_f32_16x16x32_bf16(af[mi][kk], bf[ni][kk], acc[mi+4][ni+2], 0, 0, 0);
    __builtin_amdgcn_s_setprio(0);

    // ---- p3: B(ni0-1) re-read -> acc[4-7][0-1] ----
    #pragma unroll
    for (int ni = 0; ni < 2; ni++)
      #pragma unroll
      for (int kk = 0; kk < 2; kk++)
        bf[ni][kk] = *reinterpret_cast<const short8*>(
          &Bb[(wc*64 + ni*16 + lo) * 64 + ((((kk<<2)+hi) ^ sx) << 3)]);
    __builtin_amdgcn_s_setprio(1);
    #pragma unroll
    for (int mi = 0; mi < 4; mi++)
      #pragma unroll
      for (int ni = 0; ni < 2; ni++)
        #pragma unroll
        for (int kk = 0; kk < 2; kk++)
          acc[mi+4][ni] = __builtin_amdgcn_mfma_f32_16x16x32_bf16(af[mi][kk], bf[ni][kk], acc[mi+4][ni], 0, 0, 0);
    __builtin_amdgcn_s_setprio(0);
  }
  #undef STAGE256

  // ---- epilogue (C/D: col=lane&15, row=(lane>>4)*4+rg) ----
  #pragma unroll
  for (int mi = 0; mi < 8; mi++){
    #pragma unroll
    for (int ni = 0; ni < 4; ni++){
      #pragma unroll
      for (int rg = 0; rg < 4; rg++){
        long rowg = bm + wr*128 + mi*16 + hi*4 + rg;
        long colg = bn + wc*64 + ni*16 + lo;
        float v = acc[mi][ni][rg] + bias[colg];
        if (MODE == 0){
          int part = (int)(colg >> 10), cc = (int)(colg & 1023);
          int h = cc >> 6, d = cc & 63;
          long b = rowg >> 11, t = rowg & 2047;
          if (part == 0) v *= 0.18033688f;   // 0.125 * log2(e): S lands in exp2 domain
          u16* dst = (part == 0) ? Qo : ((part == 1) ? Ko : Vo);
          dst[(((b << 4) + h) * 2048 + t) * 64 + d] = f2bf(v);
        } else {
          Cf[rowg * (long)N + colg] = v;
        }
      }
    }
  }
}

// ---------------- V transpose: [bh][t][d] -> [bh][d][t] ----------------
__global__ __launch_bounds__(256)
void vtrans_kernel(const u16* __restrict__ V, u16* __restrict__ Vt){
  __shared__ u16 Ls[64][72];
  const int bh = blockIdx.y;
  const int t0 = blockIdx.x * 64;
  const u16* Vb = V + ((size_t)bh * 2048 + t0) * 64;
  u16* Ob = Vt + (size_t)bh * 64 * 2048 + t0;
  const int r = threadIdx.x >> 3;        // 0..31
  const int c = (threadIdx.x & 7) * 8;   // 0..56
  #pragma unroll
  for (int rr = 0; rr < 64; rr += 32){
    int row = r + rr;
    *reinterpret_cast<short8*>(&Ls[row][c ^ (((row >> 4) & 3) << 4)]) =
      *reinterpret_cast<const short8*>(&Vb[(size_t)row * 64 + c]);
  }
  __syncthreads();
  const int d  = threadIdx.x >> 2;       // 0..63
  const int tc = (threadIdx.x & 3) * 16; // 0,16,32,48
  const int v  = ((tc >> 4) & 3) << 4;
  short8 o0, o1;
  #pragma unroll
  for (int j = 0; j < 8; j++) o0[j] = (short)Ls[tc + j][d ^ v];
  #pragma unroll
  for (int j = 0; j < 8; j++) o1[j] = (short)Ls[tc + 8 + j][d ^ v];
  *reinterpret_cast<short8*>(&Ob[(size_t)d * 2048 + tc]) = o0;
  *reinterpret_cast<short8*>(&Ob[(size_t)d * 2048 + tc + 8]) = o1;
}

// ---------------- causal flash attention: swapped 32x32 MFMA, in-reg softmax ----
// R10 kernel VERBATIM (best measured: 140.8 us). LPT qg = 15-(blk>>6); T5
// setprio; KVBLK=64; VGPR 72.
__global__ __launch_bounds__(256, 2)
void attn_kernel(const u16* __restrict__ Q, const u16* __restrict__ K,
                 const u16* __restrict__ Vt, u16* __restrict__ Y)
{
  const int blk = blockIdx.x;            // 0..1023
  const int bh = (blk & 7) * 8 + ((blk >> 3) & 7);  // 8 bh per XCD (4MB KV in L2)
  const int qg = 15 - (blk >> 6);        // LPT: longest (qg=15) first
  const int tid = threadIdx.x, wave = tid >> 6, lane = tid & 63;
  const int l31 = lane & 31, h5 = lane >> 5;
  const int qc = qg * 4 + wave;          // 0..63
  const int q0w = qc * 32;
  const int qrow = q0w + l31;            // this lane's q row
  const u16* Qb = Q  + (size_t)bh * 2048 * 64;
  const u16* Kb = K  + (size_t)bh * 2048 * 64;
  const u16* Vb = Vt + (size_t)bh * 64 * 2048;

  // Q^T B-frags: col=q=lane&31, k(d) = ks*16 + h5*8 + j
  short8 qf[4];
  #pragma unroll
  for (int ks = 0; ks < 4; ks++)
    qf[ks] = *reinterpret_cast<const short8*>(&Qb[(size_t)qrow * 64 + ks * 16 + h5 * 8]);

  f32x16 o0, o1;
  #pragma unroll
  for (int i = 0; i < 16; i++){ o0[i] = 0.f; o1[i] = 0.f; }
  float m = -1e30f, l = 0.f;

  const int F = qc >> 1;                 // diagonal tile index

  for (int jt = 0; jt <= F; jt++){
    const int k0 = jt << 6;

    // ---- K A-frags: row=kv(lane&31), k(d)=ks*16+h5*8+j ; 2 kv-blocks of 32 ----
    short8 kf0[4], kf1[4];
    #pragma unroll
    for (int ks = 0; ks < 4; ks++){
      kf0[ks] = *reinterpret_cast<const short8*>(&Kb[(size_t)(k0 + l31) * 64 + ks * 16 + h5 * 8]);
      kf1[ks] = *reinterpret_cast<const short8*>(&Kb[(size_t)(k0 + 32 + l31) * 64 + ks * 16 + h5 * 8]);
    }
    // ---- S^T = K . Q^T : col=q, row=kv=(r&3)+8*(r>>2)+4*h5 (+32*n) ----
    f32x16 st0, st1;
    #pragma unroll
    for (int i = 0; i < 16; i++){ st0[i] = 0.f; st1[i] = 0.f; }
    __builtin_amdgcn_s_setprio(1);
    #pragma unroll
    for (int ks = 0; ks < 4; ks++)
      st0 = __builtin_amdgcn_mfma_f32_32x32x16_bf16(kf0[ks], qf[ks], st0, 0, 0, 0);
    #pragma unroll
    for (int ks = 0; ks < 4; ks++)
      st1 = __builtin_amdgcn_mfma_f32_32x32x16_bf16(kf1[ks], qf[ks], st1, 0, 0, 0);
    __builtin_amdgcn_s_setprio(0);

    // ---- V^T A-frags issued early: row=d, k(kv)=ks*16+h5*8+j ----
    short8 vf0[4], vf1[4];
    #pragma unroll
    for (int ks = 0; ks < 4; ks++){
      vf0[ks] = *reinterpret_cast<const short8*>(&Vb[(size_t)l31 * 2048 + k0 + ks * 16 + h5 * 8]);
      vf1[ks] = *reinterpret_cast<const short8*>(&Vb[(size_t)(32 + l31) * 2048 + k0 + ks * 16 + h5 * 8]);
    }

    // ---- causal mask (diagonal tile only) ----
    if (jt == F){
      #pragma unroll
      for (int r = 0; r < 16; r++){
        int kvr = k0 + (r & 3) + 8 * (r >> 2) + 4 * h5;
        if (kvr > qrow)      st0[r] = -1e30f;
        if (kvr + 32 > qrow) st1[r] = -1e30f;
      }
    }

    // ---- in-register online softmax (one q-row per lane), rescale every tile ----
    float t[16];
    #pragma unroll
    for (int r = 0; r < 16; r++) t[r] = fmaxf(st0[r], st1[r]);
    #pragma unroll
    for (int s = 8; s > 0; s >>= 1)
      #pragma unroll
      for (int r = 0; r < 8; r++) if (r < s) t[r] = fmaxf(t[r], t[r + s]);
    float rm = fmaxf(t[0], __shfl_xor(t[0], 32));
    float mn = fmaxf(m, rm);
    float alpha = __builtin_amdgcn_exp2f(m - mn);
    m = mn;
    float rs = 0.f;
    #pragma unroll
    for (int r = 0; r < 16; r++){
      st0[r] = __builtin_amdgcn_exp2f(st0[r] - mn);
      st1[r] = __builtin_amdgcn_exp2f(st1[r] - mn);
      rs += st0[r] + st1[r];
    }
    rs += __shfl_xor(rs, 32);
    l = l * alpha + rs;
    #pragma unroll
    for (int i = 0; i < 16; i++){ o0[i] *= alpha; o1[i] *= alpha; }

    // ---- pack P^T B-frags: pa[ks2][e] = P[q][ks2*16 + h5*8 + e] (T12 exchange) ----
    short8 pa[4];
    #pragma unroll
    for (int ks2 = 0; ks2 < 4; ks2++){
      const f32x16& sv = (ks2 < 2) ? st0 : st1;
      const int gg = 8 * (ks2 & 1);
      u32 w0 = cvtpk(sv[gg + 0], sv[gg + 1]);
      u32 w1 = cvtpk(sv[gg + 2], sv[gg + 3]);
      u32 w2 = cvtpk(sv[gg + 4], sv[gg + 5]);
      u32 w3 = cvtpk(sv[gg + 6], sv[gg + 7]);
      u32 sa = h5 ? w0 : w2;               // send partner what it needs
      u32 sb = h5 ? w1 : w3;
      u32 ra = (u32)__shfl_xor((int)sa, 32);
      u32 rb = (u32)__shfl_xor((int)sb, 32);
      u32x4 pw;
      pw.x = h5 ? ra : w0;
      pw.y = h5 ? rb : w1;
      pw.z = h5 ? w2 : ra;
      pw.w = h5 ? w3 : rb;
      pa[ks2] = __builtin_bit_cast(short8, pw);
    }

    // ---- O^T += V^T . P^T ----
    __builtin_amdgcn_s_setprio(1);
    #pragma unroll
    for (int ks = 0; ks < 4; ks++)
      o0 = __builtin_amdgcn_mfma_f32_32x32x16_bf16(vf0[ks], pa[ks], o0, 0, 0, 0);
    #pragma unroll
    for (int ks = 0; ks < 4; ks++)
      o1 = __builtin_amdgcn_mfma_f32_32x32x16_bf16(vf1[ks], pa[ks], o1, 0, 0, 0);
    __builtin_amdgcn_s_setprio(0);
  }

  // ---- epilogue: O^T lane holds col q=l31, rows d = (r&3)+8*(r>>2)+4*h5 (+32) ----
  const int b = bh >> 4, h = bh & 15;
  const float inv = 1.f / l;
  u16* Yr = Y + ((size_t)(b * 2048 + qrow)) * 1024 + h * 64;
  #pragma unroll
  for (int rq = 0; rq < 4; rq++){
    ushort4 ua, ub;
    #pragma unroll
    for (int e = 0; e < 4; e++){
      ((u16*)&ua)[e] = f2bf(o0[rq * 4 + e] * inv);
      ((u16*)&ub)[e] = f2bf(o1[rq * 4 + e] * inv);
    }
    *reinterpret_cast<ushort4*>(&Yr[rq * 8 + h5 * 4])      = ua;
    *reinterpret_cast<ushort4*>(&Yr[32 + rq * 8 + h5 * 4]) = ub;
  }
}

// ---------------- launch ----------------
extern "C" void kernel_launch(void* const* d_in, const int* in_sizes, int n_in,
                              void* d_out, int out_size, void* d_ws, size_t ws_size,
                              hipStream_t stream)
{
  const float* x      = (const float*)d_in[0];
  const float* w_qkv  = (const float*)d_in[1];
  const float* b_qkv  = (const float*)d_in[2];
  const float* w_proj = (const float*)d_in[3];
  const float* b_proj = (const float*)d_in[4];
  float* out = (float*)d_out;

  char* ws = (char*)d_ws;
  u16* xb     = (u16*)(ws);                       // 16 MB  [8192,1024]  (reused as vtb)
  u16* wqkvb  = (u16*)(ws + (16u << 20));         //  6 MB  [3072,1024]
  u16* wprojb = (u16*)(ws + (22u << 20));         //  2 MB  [1024,1024]
  u16* qb     = (u16*)(ws + (24u << 20));         // 16 MB  [64,2048,64]
  u16* kb     = (u16*)(ws + (40u << 20));         // 16 MB
  u16* vb     = (u16*)(ws + (56u << 20));         // 16 MB
  u16* yb     = (u16*)(ws + (72u << 20));         // 16 MB  [8192,1024]
  u16* vtb    = xb;                               // 16 MB  [64,64,2048] (after GEMM1, xb is dead)

  // fused converts: 12288 blocks cover x + w_qkv + w_proj float4s
  cvt3_kernel<<<12288, 256, 0, stream>>>(x, w_qkv, w_proj, xb, wqkvb, wprojb);

  // GEMM1: M=8192, N=3072 -> 32x12 = 384 blocks (%8==0)
  gemm256<0><<<384, 512, 0, stream>>>(xb, wqkvb, b_qkv, nullptr, qb, kb, vb, 3072, C_);

  dim3 gt(T_ / 64, B_ * H_);
  vtrans_kernel<<<gt, 256, 0, stream>>>(vb, vtb);

  attn_kernel<<<1024, 256, 0, stream>>>(qb, kb, vtb, yb);

  // GEMM2: M=8192, N=1024 -> 32x4 = 128 blocks (%8==0)
  gemm256<1><<<128, 512, 0, stream>>>(yb, wprojb, b_proj, out, nullptr, nullptr, nullptr, C_, C_);
}